// Round 5
// baseline (421.325 us; speedup 1.0000x reference)
//
#include <hip/hip_runtime.h>

// CommNet, fully transposed MFMA formulation (K=16 chunks).
// Key identity: for mfma_f32_16x16x16bf16, B[k=quad*4+i][n=lane&15] has the SAME
// lane/k indexing as C/D [row=quad*4+reg][col=lane&15] -> layer outputs convert to
// next layer's B-frags with pure in-lane cvt+pack (no LDS round-trip, no shfl).
// msg term: concat([h,msg])@W == h@(Wtop - Wbot/31) + S@(Wbot/31), S = sum_agents h.
// S is folded in as 4 extra K-chunks whose B-frag is S replicated across columns,
// obtained by a 4-step shfl_xor column butterfly (cols = agents in transposed form).

typedef __attribute__((ext_vector_type(4))) short bf16x4;
typedef __attribute__((ext_vector_type(8))) short bf16x8;
typedef __attribute__((ext_vector_type(4))) float f32x4;
typedef __attribute__((ext_vector_type(4))) int i32x4;
typedef unsigned int u32;

__device__ __forceinline__ short f2bf(float f) {        // truncate (activations)
  return (short)(__float_as_uint(f) >> 16);
}
__device__ __forceinline__ short f2bf_rne(float f) {    // RNE (weights, done once)
  u32 u = __float_as_uint(f);
  return (short)((u + 0x7fffu + ((u >> 16) & 1u)) >> 16);
}

#define MFMA16(A, B, C) __builtin_amdgcn_mfma_f32_16x16x16bf16_1k(A, B, C, 0, 0, 0)

__device__ __forceinline__ bf16x4 plo(bf16x8 p) {
  bf16x4 r; r[0] = p[0]; r[1] = p[1]; r[2] = p[2]; r[3] = p[3]; return r;
}
__device__ __forceinline__ bf16x4 phi(bf16x8 p) {
  bf16x4 r; r[0] = p[4]; r[1] = p[5]; r[2] = p[6]; r[3] = p[7]; return r;
}

// ---------------------------------------------------------------------------
// Weight packing: 50 "pair" frags of 512 shorts. Pair f, lane, half c (0/1), j:
// element = A16-chunk(2f+c): A[m=col][k_local=quad*4+j] of the transposed weight.
// (A-layout of W^T == B-layout of W, so values are W[k][n] as before.)
//   f 0..7  : enc_w     (kk=f>>2, mf=f&3)
//   f 8..23 : W_eff[r] = Wtop - Wbot/31
//   f 24..39: V[r]     = Wbot/31      (the S chunks)
//   f 40..47: out_w1
//   f 48..49: out_w2    (mf=0 only)
// ---------------------------------------------------------------------------
__global__ void build_frags(const float* __restrict__ enc_w, const float* __restrict__ comm_w,
                            const float* __restrict__ w1, const float* __restrict__ w2,
                            short* __restrict__ wf) {
  int e = blockIdx.x * blockDim.x + threadIdx.x;
  if (e >= 50 * 512) return;
  int f = e >> 9, i9 = e & 511;
  int lane = i9 >> 3, c = (i9 >> 2) & 1, j = i9 & 3;
  int quad = lane >> 4, col = lane & 15;
  int kl = c * 16 + quad * 4 + j;   // k within the 32-wide (kk) slice
  float val;
  if (f < 8) {
    int kk = f >> 2, mf = f & 3;
    val = enc_w[(kk * 32 + kl) * 64 + mf * 16 + col];
  } else if (f < 24) {
    int g = f - 8, r = g >> 3, kk = (g >> 2) & 1, mf = g & 3;
    const float* W = comm_w + r * 8192;
    int k = kk * 32 + kl, n = mf * 16 + col;
    val = W[k * 64 + n] - W[(64 + k) * 64 + n] * (1.0f / 31.0f);
  } else if (f < 40) {
    int g = f - 24, r = g >> 3, kk = (g >> 2) & 1, mf = g & 3;
    const float* W = comm_w + r * 8192;
    val = W[(64 + kk * 32 + kl) * 64 + mf * 16 + col] * (1.0f / 31.0f);
  } else if (f < 48) {
    int g = f - 40, kk = (g >> 2) & 1, mf = g & 3;
    val = w1[(kk * 32 + kl) * 64 + mf * 16 + col];
  } else {
    int kk = f - 48;
    val = w2[(kk * 32 + kl) * 16 + col];
  }
  wf[e] = f2bf_rne(val);
}

// bias+relu on C-layout accs, in-lane repack to next-layer B-frags; optional
// agent-column butterfly producing the replicated S frags.
template<bool WITH_S>
__device__ __forceinline__ void stage16(const f32x4 (&ya)[4][2], const float* bias, int quad,
                                        bf16x4 (&bh)[4][2], bf16x4 (&bs)[4]) {
  f32x4 s[4];
#pragma unroll
  for (int mf = 0; mf < 4; mf++) {
    f32x4 bv = *(const f32x4*)(bias + mf * 16 + quad * 4);
#pragma unroll
    for (int na = 0; na < 2; na++) {
      f32x4 v;
#pragma unroll
      for (int r2 = 0; r2 < 4; r2++) v[r2] = fmaxf(ya[mf][na][r2] + bv[r2], 0.0f);
      bf16x4 h; h[0] = f2bf(v[0]); h[1] = f2bf(v[1]); h[2] = f2bf(v[2]); h[3] = f2bf(v[3]);
      bh[mf][na] = h;
      if constexpr (WITH_S) {
        if (na == 0) s[mf] = v;
        else { s[mf][0] += v[0]; s[mf][1] += v[1]; s[mf][2] += v[2]; s[mf][3] += v[3]; }
      }
    }
  }
  if constexpr (WITH_S) {
    // sum over the 16 agent columns (xor bits 0..3 never cross quads)
#pragma unroll
    for (int st = 1; st < 16; st <<= 1)
#pragma unroll
      for (int mf = 0; mf < 4; mf++)
#pragma unroll
        for (int r2 = 0; r2 < 4; r2++) s[mf][r2] += __shfl_xor(s[mf][r2], st);
#pragma unroll
    for (int mf = 0; mf < 4; mf++) {
      bf16x4 t; t[0] = f2bf(s[mf][0]); t[1] = f2bf(s[mf][1]);
      t[2] = f2bf(s[mf][2]); t[3] = f2bf(s[mf][3]);
      bs[mf] = t;   // identical in all 16 cols == replicated S chunk, as the MFMA needs
    }
  }
}

__global__ void __launch_bounds__(256, 3) commnet_main(
    const float* __restrict__ obs,
    const float* __restrict__ enc_b,
    const float* __restrict__ comm_b,
    const float* __restrict__ ob1,
    const float* __restrict__ ob2,
    const int* __restrict__ avail,
    const short* __restrict__ wfr,
    float* __restrict__ out) {
  __shared__ short lw[50 * 512];   // 51200 B weight pair-frags
  __shared__ float lb[272];        // 0:enc_b 64:comm_b(128) 192:out_b1 256:out_b2
  const int tid = threadIdx.x, wave = tid >> 6, lane = tid & 63;
  const int quad = lane >> 4, col = lane & 15;
  const bf16x8* wf8 = (const bf16x8*)wfr;

#pragma unroll 1
  for (int f = wave; f < 50; f += 4)
    *(bf16x8*)(lw + f * 512 + lane * 8) = wf8[f * 64 + lane];
  if (tid < 64)        lb[tid] = enc_b[tid];
  else if (tid < 192)  lb[tid] = comm_b[tid - 64];
  else if (tid < 256)  lb[tid] = ob1[tid - 192];
  if (tid < 16)        lb[256 + tid] = ob2[tid];
  __syncthreads();

  int b = blockIdx.x * 4 + wave;   // grid 2048 x 4 waves = 8192; 2 iters cover 16384
  f32x4 po[2][4];                  // obs^T B-frag sources [na][kk16], one f32x4 each
  i32x4 pav[2];
#pragma unroll
  for (int na = 0; na < 2; na++) {
#pragma unroll
    for (int k = 0; k < 4; k++)
      po[na][k] = *(const f32x4*)(obs + ((b * 32 + na * 16 + col) * 64 + k * 16 + quad * 4));
    pav[na] = *(const i32x4*)(avail + ((b * 32 + na * 16 + col) * 16 + quad * 4));
  }

#pragma unroll 1
  for (int it = 0; it < 2; it++) {
    const int bn = (it == 0) ? (b + 8192) : 0;   // last iter: dummy L2-hot prefetch

    bf16x4 bh[4][2], bs[4];
    // obs f32 -> bf16 B-frags (pure in-lane)
#pragma unroll
    for (int k = 0; k < 4; k++)
#pragma unroll
      for (int na = 0; na < 2; na++) {
        f32x4 x = po[na][k];
        bf16x4 h; h[0] = f2bf(x[0]); h[1] = f2bf(x[1]); h[2] = f2bf(x[2]); h[3] = f2bf(x[3]);
        bh[k][na] = h;
      }

    const f32x4 z4 = {0.f, 0.f, 0.f, 0.f};
    f32x4 ya[4][2];

    // ---------------- GEMM1: h0^T = relu(enc_w^T obs^T + b) ----------------
#pragma unroll
    for (int mf = 0; mf < 4; mf++) { ya[mf][0] = z4; ya[mf][1] = z4; }
#pragma unroll
    for (int kp = 0; kp < 2; kp++)
#pragma unroll
      for (int mf = 0; mf < 4; mf++) {
        bf16x8 P = *(const bf16x8*)(lw + (kp * 4 + mf) * 512 + lane * 8);
        bf16x4 A0 = plo(P), A1 = phi(P);
#pragma unroll
        for (int na = 0; na < 2; na++) {
          ya[mf][na] = MFMA16(A0, bh[2 * kp][na], ya[mf][na]);
          ya[mf][na] = MFMA16(A1, bh[2 * kp + 1][na], ya[mf][na]);
        }
      }
    stage16<true>(ya, lb + 0, quad, bh, bs);

    // -------- comm rounds: Y^T = W_eff^T H^T + V^T S 1^T + b (S via extra K) ----
#pragma unroll
    for (int r = 0; r < 2; r++) {
#pragma unroll
      for (int mf = 0; mf < 4; mf++) { ya[mf][0] = z4; ya[mf][1] = z4; }
#pragma unroll
      for (int kp = 0; kp < 2; kp++)
#pragma unroll
        for (int mf = 0; mf < 4; mf++) {
          bf16x8 P = *(const bf16x8*)(lw + (8 + r * 8 + kp * 4 + mf) * 512 + lane * 8);
          bf16x8 Q = *(const bf16x8*)(lw + (24 + r * 8 + kp * 4 + mf) * 512 + lane * 8);
          bf16x4 W0 = plo(P), W1 = phi(P), V0 = plo(Q), V1 = phi(Q);
#pragma unroll
          for (int na = 0; na < 2; na++) {
            ya[mf][na] = MFMA16(W0, bh[2 * kp][na], ya[mf][na]);
            ya[mf][na] = MFMA16(W1, bh[2 * kp + 1][na], ya[mf][na]);
            ya[mf][na] = MFMA16(V0, bs[2 * kp], ya[mf][na]);
            ya[mf][na] = MFMA16(V1, bs[2 * kp + 1], ya[mf][na]);
          }
        }
      if (r == 0) stage16<true>(ya, lb + 64, quad, bh, bs);
      else        stage16<false>(ya, lb + 128, quad, bh, bs);
    }

    // ---------------- out1: hid^T = relu(w1^T h^T + b1) ---------------------
#pragma unroll
    for (int mf = 0; mf < 4; mf++) { ya[mf][0] = z4; ya[mf][1] = z4; }
#pragma unroll
    for (int kp = 0; kp < 2; kp++)
#pragma unroll
      for (int mf = 0; mf < 4; mf++) {
        bf16x8 P = *(const bf16x8*)(lw + (40 + kp * 4 + mf) * 512 + lane * 8);
        bf16x4 A0 = plo(P), A1 = phi(P);
#pragma unroll
        for (int na = 0; na < 2; na++) {
          ya[mf][na] = MFMA16(A0, bh[2 * kp][na], ya[mf][na]);
          ya[mf][na] = MFMA16(A1, bh[2 * kp + 1][na], ya[mf][na]);
        }
      }
    stage16<false>(ya, lb + 192, quad, bh, bs);

    // prefetch next batch's obs now (ya dead, low pressure region)
#pragma unroll
    for (int na = 0; na < 2; na++)
#pragma unroll
      for (int k = 0; k < 4; k++)
        po[na][k] = *(const f32x4*)(obs + ((bn * 32 + na * 16 + col) * 64 + k * 16 + quad * 4));

    // ---------------- out2 + mask + vectorized store ------------------------
    f32x4 q[2] = {z4, z4};
#pragma unroll
    for (int kp = 0; kp < 2; kp++) {
      bf16x8 P = *(const bf16x8*)(lw + (48 + kp) * 512 + lane * 8);
      bf16x4 A0 = plo(P), A1 = phi(P);
#pragma unroll
      for (int na = 0; na < 2; na++) {
        q[na] = MFMA16(A0, bh[2 * kp][na], q[na]);
        q[na] = MFMA16(A1, bh[2 * kp + 1][na], q[na]);
      }
    }
    f32x4 obv = *(const f32x4*)(lb + 256 + quad * 4);
#pragma unroll
    for (int na = 0; na < 2; na++) {
      int base = (b * 32 + na * 16 + col) * 16 + quad * 4;
      f32x4 v;
#pragma unroll
      for (int r2 = 0; r2 < 4; r2++)
        v[r2] = (pav[na][r2] == 0) ? -1e10f : (q[na][r2] + obv[r2]);
      *(f32x4*)(out + base) = v;
      pav[na] = *(const i32x4*)(avail + ((bn * 32 + na * 16 + col) * 16 + quad * 4));
    }
    b = bn;
  }
}

extern "C" void kernel_launch(void* const* d_in, const int* in_sizes, int n_in,
                              void* d_out, int out_size, void* d_ws, size_t ws_size,
                              hipStream_t stream) {
  const float* obs    = (const float*)d_in[0];
  const float* enc_w  = (const float*)d_in[1];
  const float* enc_b  = (const float*)d_in[2];
  const float* comm_w = (const float*)d_in[3];
  const float* comm_b = (const float*)d_in[4];
  const float* out_w1 = (const float*)d_in[5];
  const float* out_b1 = (const float*)d_in[6];
  const float* out_w2 = (const float*)d_in[7];
  const float* out_b2 = (const float*)d_in[8];
  const int*   avail  = (const int*)d_in[9];
  short* wf = (short*)d_ws;  // 50 pair-frags * 512 bf16 = 51200 B scratch

  build_frags<<<100, 256, 0, stream>>>(enc_w, comm_w, out_w1, out_w2, wf);
  commnet_main<<<2048, 256, 0, stream>>>(obs, enc_b, comm_b, out_b1, out_b2, avail, wf,
                                         (float*)d_out);
}

// Round 6
// 346.470 us; speedup vs baseline: 1.2160x; 1.2160x over previous
//
#include <hip/hip_runtime.h>

// CommNet, fully transposed MFMA formulation (K=16 chunks).
// Key identity: for mfma_f32_16x16x16bf16, B[k=quad*4+i][n=lane&15] has the SAME
// lane/k indexing as C/D [row=quad*4+reg][col=lane&15] -> layer outputs convert to
// next layer's B-frags with pure in-lane cvt+pack (no LDS round-trip, no shfl).
// msg term: concat([h,msg])@W == h@(Wtop - Wbot/31) + S@(Wbot/31), S = sum_agents h.
// S is folded in as 4 extra K-chunks whose B-frag is S replicated across columns,
// obtained by a 4-step shfl_xor column butterfly (cols = agents in transposed form).
//
// REGISTER BUDGET LAW (learned R2, R5): this kernel's live set needs the full
// 256-VGPR budget. (256,3) caps at 168, the MFMA split gives 84 arch + 84 acc,
// and ~95 regs spill -> +400 MB scratch traffic each way, 3x slower. Keep (256,2).

typedef __attribute__((ext_vector_type(4))) short bf16x4;
typedef __attribute__((ext_vector_type(8))) short bf16x8;
typedef __attribute__((ext_vector_type(4))) float f32x4;
typedef __attribute__((ext_vector_type(4))) int i32x4;
typedef unsigned int u32;

__device__ __forceinline__ short f2bf(float f) {        // truncate (activations)
  return (short)(__float_as_uint(f) >> 16);
}
__device__ __forceinline__ short f2bf_rne(float f) {    // RNE (weights, done once)
  u32 u = __float_as_uint(f);
  return (short)((u + 0x7fffu + ((u >> 16) & 1u)) >> 16);
}

#define MFMA16(A, B, C) __builtin_amdgcn_mfma_f32_16x16x16bf16_1k(A, B, C, 0, 0, 0)

__device__ __forceinline__ bf16x4 plo(bf16x8 p) {
  bf16x4 r; r[0] = p[0]; r[1] = p[1]; r[2] = p[2]; r[3] = p[3]; return r;
}
__device__ __forceinline__ bf16x4 phi(bf16x8 p) {
  bf16x4 r; r[0] = p[4]; r[1] = p[5]; r[2] = p[6]; r[3] = p[7]; return r;
}

// ---------------------------------------------------------------------------
// Weight packing: 50 "pair" frags of 512 shorts. Pair f, lane, half c (0/1), j:
// element = A16-chunk(2f+c): A[m=col][k_local=quad*4+j] of the transposed weight.
//   f 0..7  : enc_w     f 8..23 : W_eff[r]=Wtop-Wbot/31
//   f 24..39: V[r]=Wbot/31 (S chunks)   f 40..47: out_w1   f 48..49: out_w2
// ---------------------------------------------------------------------------
__global__ void build_frags(const float* __restrict__ enc_w, const float* __restrict__ comm_w,
                            const float* __restrict__ w1, const float* __restrict__ w2,
                            short* __restrict__ wf) {
  int e = blockIdx.x * blockDim.x + threadIdx.x;
  if (e >= 50 * 512) return;
  int f = e >> 9, i9 = e & 511;
  int lane = i9 >> 3, c = (i9 >> 2) & 1, j = i9 & 3;
  int quad = lane >> 4, col = lane & 15;
  int kl = c * 16 + quad * 4 + j;   // k within the 32-wide (kk) slice
  float val;
  if (f < 8) {
    int kk = f >> 2, mf = f & 3;
    val = enc_w[(kk * 32 + kl) * 64 + mf * 16 + col];
  } else if (f < 24) {
    int g = f - 8, r = g >> 3, kk = (g >> 2) & 1, mf = g & 3;
    const float* W = comm_w + r * 8192;
    int k = kk * 32 + kl, n = mf * 16 + col;
    val = W[k * 64 + n] - W[(64 + k) * 64 + n] * (1.0f / 31.0f);
  } else if (f < 40) {
    int g = f - 24, r = g >> 3, kk = (g >> 2) & 1, mf = g & 3;
    const float* W = comm_w + r * 8192;
    val = W[(64 + kk * 32 + kl) * 64 + mf * 16 + col] * (1.0f / 31.0f);
  } else if (f < 48) {
    int g = f - 40, kk = (g >> 2) & 1, mf = g & 3;
    val = w1[(kk * 32 + kl) * 64 + mf * 16 + col];
  } else {
    int kk = f - 48;
    val = w2[(kk * 32 + kl) * 16 + col];
  }
  wf[e] = f2bf_rne(val);
}

// bias+relu on C-layout accs, in-lane repack to next-layer B-frags; optional
// agent-column butterfly producing the replicated S frags.
template<bool WITH_S>
__device__ __forceinline__ void stage16(const f32x4 (&ya)[4][2], const float* bias, int quad,
                                        bf16x4 (&bh)[4][2], bf16x4 (&bs)[4]) {
  f32x4 s[4];
#pragma unroll
  for (int mf = 0; mf < 4; mf++) {
    f32x4 bv = *(const f32x4*)(bias + mf * 16 + quad * 4);
#pragma unroll
    for (int na = 0; na < 2; na++) {
      f32x4 v;
#pragma unroll
      for (int r2 = 0; r2 < 4; r2++) v[r2] = fmaxf(ya[mf][na][r2] + bv[r2], 0.0f);
      bf16x4 h; h[0] = f2bf(v[0]); h[1] = f2bf(v[1]); h[2] = f2bf(v[2]); h[3] = f2bf(v[3]);
      bh[mf][na] = h;
      if constexpr (WITH_S) {
        if (na == 0) s[mf] = v;
        else { s[mf][0] += v[0]; s[mf][1] += v[1]; s[mf][2] += v[2]; s[mf][3] += v[3]; }
      }
    }
  }
  if constexpr (WITH_S) {
    // sum over the 16 agent columns (xor bits 0..3 never cross quads)
#pragma unroll
    for (int st = 1; st < 16; st <<= 1)
#pragma unroll
      for (int mf = 0; mf < 4; mf++)
#pragma unroll
        for (int r2 = 0; r2 < 4; r2++) s[mf][r2] += __shfl_xor(s[mf][r2], st);
#pragma unroll
    for (int mf = 0; mf < 4; mf++) {
      bf16x4 t; t[0] = f2bf(s[mf][0]); t[1] = f2bf(s[mf][1]);
      t[2] = f2bf(s[mf][2]); t[3] = f2bf(s[mf][3]);
      bs[mf] = t;   // identical in all 16 cols == replicated S chunk, as the MFMA needs
    }
  }
}

__global__ void __launch_bounds__(256, 2) commnet_main(
    const float* __restrict__ obs,
    const float* __restrict__ enc_b,
    const float* __restrict__ comm_b,
    const float* __restrict__ ob1,
    const float* __restrict__ ob2,
    const int* __restrict__ avail,
    const short* __restrict__ wfr,
    float* __restrict__ out) {
  __shared__ short lw[50 * 512];   // 51200 B weight pair-frags
  __shared__ float lb[272];        // 0:enc_b 64:comm_b(128) 192:out_b1 256:out_b2
  const int tid = threadIdx.x, wave = tid >> 6, lane = tid & 63;
  const int quad = lane >> 4, col = lane & 15;
  const bf16x8* wf8 = (const bf16x8*)wfr;

#pragma unroll 1
  for (int f = wave; f < 50; f += 4)
    *(bf16x8*)(lw + f * 512 + lane * 8) = wf8[f * 64 + lane];
  if (tid < 64)        lb[tid] = enc_b[tid];
  else if (tid < 192)  lb[tid] = comm_b[tid - 64];
  else if (tid < 256)  lb[tid] = ob1[tid - 192];
  if (tid < 16)        lb[256 + tid] = ob2[tid];
  __syncthreads();

  int b = blockIdx.x * 4 + wave;   // grid 2048 x 4 waves = 8192; 2 iters cover 16384
  f32x4 po[2][4];                  // obs^T B-frag sources [na][kk16], one f32x4 each
  i32x4 pav[2];
#pragma unroll
  for (int na = 0; na < 2; na++) {
#pragma unroll
    for (int k = 0; k < 4; k++)
      po[na][k] = *(const f32x4*)(obs + ((b * 32 + na * 16 + col) * 64 + k * 16 + quad * 4));
    pav[na] = *(const i32x4*)(avail + ((b * 32 + na * 16 + col) * 16 + quad * 4));
  }

#pragma unroll 1
  for (int it = 0; it < 2; it++) {
    const int bn = (it == 0) ? (b + 8192) : 0;   // last iter: dummy L2-hot prefetch

    bf16x4 bh[4][2], bs[4];
    // obs f32 -> bf16 B-frags (pure in-lane)
#pragma unroll
    for (int k = 0; k < 4; k++)
#pragma unroll
      for (int na = 0; na < 2; na++) {
        f32x4 x = po[na][k];
        bf16x4 h; h[0] = f2bf(x[0]); h[1] = f2bf(x[1]); h[2] = f2bf(x[2]); h[3] = f2bf(x[3]);
        bh[k][na] = h;
      }

    const f32x4 z4 = {0.f, 0.f, 0.f, 0.f};
    f32x4 ya[4][2];

    // ---------------- GEMM1: h0^T = relu(enc_w^T obs^T + b) ----------------
#pragma unroll
    for (int mf = 0; mf < 4; mf++) { ya[mf][0] = z4; ya[mf][1] = z4; }
#pragma unroll
    for (int kp = 0; kp < 2; kp++)
#pragma unroll
      for (int mf = 0; mf < 4; mf++) {
        bf16x8 P = *(const bf16x8*)(lw + (kp * 4 + mf) * 512 + lane * 8);
        bf16x4 A0 = plo(P), A1 = phi(P);
#pragma unroll
        for (int na = 0; na < 2; na++) {
          ya[mf][na] = MFMA16(A0, bh[2 * kp][na], ya[mf][na]);
          ya[mf][na] = MFMA16(A1, bh[2 * kp + 1][na], ya[mf][na]);
        }
      }
    stage16<true>(ya, lb + 0, quad, bh, bs);

    // -------- comm rounds: Y^T = W_eff^T H^T + V^T S 1^T + b (S via extra K) ----
#pragma unroll
    for (int r = 0; r < 2; r++) {
#pragma unroll
      for (int mf = 0; mf < 4; mf++) { ya[mf][0] = z4; ya[mf][1] = z4; }
#pragma unroll
      for (int kp = 0; kp < 2; kp++)
#pragma unroll
        for (int mf = 0; mf < 4; mf++) {
          bf16x8 P = *(const bf16x8*)(lw + (8 + r * 8 + kp * 4 + mf) * 512 + lane * 8);
          bf16x8 Q = *(const bf16x8*)(lw + (24 + r * 8 + kp * 4 + mf) * 512 + lane * 8);
          bf16x4 W0 = plo(P), W1 = phi(P), V0 = plo(Q), V1 = phi(Q);
#pragma unroll
          for (int na = 0; na < 2; na++) {
            ya[mf][na] = MFMA16(W0, bh[2 * kp][na], ya[mf][na]);
            ya[mf][na] = MFMA16(W1, bh[2 * kp + 1][na], ya[mf][na]);
            ya[mf][na] = MFMA16(V0, bs[2 * kp], ya[mf][na]);
            ya[mf][na] = MFMA16(V1, bs[2 * kp + 1], ya[mf][na]);
          }
        }
      if (r == 0) stage16<true>(ya, lb + 64, quad, bh, bs);
      else        stage16<false>(ya, lb + 128, quad, bh, bs);
    }

    // ---------------- out1: hid^T = relu(w1^T h^T + b1) ---------------------
#pragma unroll
    for (int mf = 0; mf < 4; mf++) { ya[mf][0] = z4; ya[mf][1] = z4; }
#pragma unroll
    for (int kp = 0; kp < 2; kp++)
#pragma unroll
      for (int mf = 0; mf < 4; mf++) {
        bf16x8 P = *(const bf16x8*)(lw + (40 + kp * 4 + mf) * 512 + lane * 8);
        bf16x4 A0 = plo(P), A1 = phi(P);
#pragma unroll
        for (int na = 0; na < 2; na++) {
          ya[mf][na] = MFMA16(A0, bh[2 * kp][na], ya[mf][na]);
          ya[mf][na] = MFMA16(A1, bh[2 * kp + 1][na], ya[mf][na]);
        }
      }
    stage16<false>(ya, lb + 192, quad, bh, bs);

    // prefetch next batch's obs now (ya dead, low pressure region)
#pragma unroll
    for (int na = 0; na < 2; na++)
#pragma unroll
      for (int k = 0; k < 4; k++)
        po[na][k] = *(const f32x4*)(obs + ((bn * 32 + na * 16 + col) * 64 + k * 16 + quad * 4));

    // ---------------- out2 + mask + vectorized store ------------------------
    f32x4 q[2] = {z4, z4};
#pragma unroll
    for (int kp = 0; kp < 2; kp++) {
      bf16x8 P = *(const bf16x8*)(lw + (48 + kp) * 512 + lane * 8);
      bf16x4 A0 = plo(P), A1 = phi(P);
#pragma unroll
      for (int na = 0; na < 2; na++) {
        q[na] = MFMA16(A0, bh[2 * kp][na], q[na]);
        q[na] = MFMA16(A1, bh[2 * kp + 1][na], q[na]);
      }
    }
    f32x4 obv = *(const f32x4*)(lb + 256 + quad * 4);
#pragma unroll
    for (int na = 0; na < 2; na++) {
      int base = (b * 32 + na * 16 + col) * 16 + quad * 4;
      f32x4 v;
#pragma unroll
      for (int r2 = 0; r2 < 4; r2++)
        v[r2] = (pav[na][r2] == 0) ? -1e10f : (q[na][r2] + obv[r2]);
      *(f32x4*)(out + base) = v;
      pav[na] = *(const i32x4*)(avail + ((bn * 32 + na * 16 + col) * 16 + quad * 4));
    }
    b = bn;
  }
}

extern "C" void kernel_launch(void* const* d_in, const int* in_sizes, int n_in,
                              void* d_out, int out_size, void* d_ws, size_t ws_size,
                              hipStream_t stream) {
  const float* obs    = (const float*)d_in[0];
  const float* enc_w  = (const float*)d_in[1];
  const float* enc_b  = (const float*)d_in[2];
  const float* comm_w = (const float*)d_in[3];
  const float* comm_b = (const float*)d_in[4];
  const float* out_w1 = (const float*)d_in[5];
  const float* out_b1 = (const float*)d_in[6];
  const float* out_w2 = (const float*)d_in[7];
  const float* out_b2 = (const float*)d_in[8];
  const int*   avail  = (const int*)d_in[9];
  short* wf = (short*)d_ws;  // 50 pair-frags * 512 bf16 = 51200 B scratch

  build_frags<<<100, 256, 0, stream>>>(enc_w, comm_w, out_w1, out_w2, wf);
  commnet_main<<<2048, 256, 0, stream>>>(obs, enc_b, comm_b, out_b1, out_b2, avail, wf,
                                         (float*)d_out);
}

// Round 7
// 249.173 us; speedup vs baseline: 1.6909x; 1.3905x over previous
//
#include <hip/hip_runtime.h>

// CommNet, fully transposed MFMA formulation (K=16 chunks).
// Key identity: for mfma_f32_16x16x16bf16, B[k=quad*4+i][n=lane&15] has the SAME
// lane/k indexing as C/D [row=quad*4+reg][col=lane&15] -> layer outputs convert to
// next layer's B-frags with pure in-lane cvt+pack (no LDS round-trip, no shfl).
// msg term: concat([h,msg])@W == h@(Wtop - Wbot/31) + S@(Wbot/31), S = sum_agents h.
// S is folded in as 4 extra K-chunks whose B-frag is S replicated across columns
// (4-step shfl_xor column butterfly; cols = agents in transposed form).
//
// REGISTER BUDGET LAW (R2, R5, R6): the compiler splits the unified 512-file
// into arch+acc halves (128+128 at (256,2)); the ARCH half is the binding
// constraint. Any value held across the unrolled body costs arch regs and
// risks scratch spill (R6: po/pav prefetch window -> 215 MB spill writes).
// Hence: one batch per wave, inputs converted/consumed immediately, no
// cross-body prefetch. TLP (8 waves/CU) hides input latency (proved R1/R3:
// prefetch was neutral).

typedef __attribute__((ext_vector_type(4))) short bf16x4;
typedef __attribute__((ext_vector_type(8))) short bf16x8;
typedef __attribute__((ext_vector_type(4))) float f32x4;
typedef __attribute__((ext_vector_type(4))) int i32x4;
typedef unsigned int u32;

__device__ __forceinline__ short f2bf(float f) {        // truncate (activations)
  return (short)(__float_as_uint(f) >> 16);
}
__device__ __forceinline__ short f2bf_rne(float f) {    // RNE (weights, done once)
  u32 u = __float_as_uint(f);
  return (short)((u + 0x7fffu + ((u >> 16) & 1u)) >> 16);
}

#define MFMA16(A, B, C) __builtin_amdgcn_mfma_f32_16x16x16bf16_1k(A, B, C, 0, 0, 0)

__device__ __forceinline__ bf16x4 plo(bf16x8 p) {
  bf16x4 r; r[0] = p[0]; r[1] = p[1]; r[2] = p[2]; r[3] = p[3]; return r;
}
__device__ __forceinline__ bf16x4 phi(bf16x8 p) {
  bf16x4 r; r[0] = p[4]; r[1] = p[5]; r[2] = p[6]; r[3] = p[7]; return r;
}

// ---------------------------------------------------------------------------
// Weight packing: 50 "pair" frags of 512 shorts. Pair f, lane, half c (0/1), j:
// element = A16-chunk(2f+c): A[m=col][k_local=quad*4+j] of the transposed weight.
//   f 0..7  : enc_w     f 8..23 : W_eff[r]=Wtop-Wbot/31
//   f 24..39: V[r]=Wbot/31 (S chunks)   f 40..47: out_w1   f 48..49: out_w2
// ---------------------------------------------------------------------------
__global__ void build_frags(const float* __restrict__ enc_w, const float* __restrict__ comm_w,
                            const float* __restrict__ w1, const float* __restrict__ w2,
                            short* __restrict__ wf) {
  int e = blockIdx.x * blockDim.x + threadIdx.x;
  if (e >= 50 * 512) return;
  int f = e >> 9, i9 = e & 511;
  int lane = i9 >> 3, c = (i9 >> 2) & 1, j = i9 & 3;
  int quad = lane >> 4, col = lane & 15;
  int kl = c * 16 + quad * 4 + j;   // k within the 32-wide (kk) slice
  float val;
  if (f < 8) {
    int kk = f >> 2, mf = f & 3;
    val = enc_w[(kk * 32 + kl) * 64 + mf * 16 + col];
  } else if (f < 24) {
    int g = f - 8, r = g >> 3, kk = (g >> 2) & 1, mf = g & 3;
    const float* W = comm_w + r * 8192;
    int k = kk * 32 + kl, n = mf * 16 + col;
    val = W[k * 64 + n] - W[(64 + k) * 64 + n] * (1.0f / 31.0f);
  } else if (f < 40) {
    int g = f - 24, r = g >> 3, kk = (g >> 2) & 1, mf = g & 3;
    const float* W = comm_w + r * 8192;
    val = W[(64 + kk * 32 + kl) * 64 + mf * 16 + col] * (1.0f / 31.0f);
  } else if (f < 48) {
    int g = f - 40, kk = (g >> 2) & 1, mf = g & 3;
    val = w1[(kk * 32 + kl) * 64 + mf * 16 + col];
  } else {
    int kk = f - 48;
    val = w2[(kk * 32 + kl) * 16 + col];
  }
  wf[e] = f2bf_rne(val);
}

// bias+relu on C-layout accs, in-lane repack to next-layer B-frags; optional
// agent-column butterfly producing the replicated S frags.
template<bool WITH_S>
__device__ __forceinline__ void stage16(const f32x4 (&ya)[4][2], const float* bias, int quad,
                                        bf16x4 (&bh)[4][2], bf16x4 (&bs)[4]) {
  f32x4 s[4];
#pragma unroll
  for (int mf = 0; mf < 4; mf++) {
    f32x4 bv = *(const f32x4*)(bias + mf * 16 + quad * 4);
#pragma unroll
    for (int na = 0; na < 2; na++) {
      f32x4 v;
#pragma unroll
      for (int r2 = 0; r2 < 4; r2++) v[r2] = fmaxf(ya[mf][na][r2] + bv[r2], 0.0f);
      bf16x4 h; h[0] = f2bf(v[0]); h[1] = f2bf(v[1]); h[2] = f2bf(v[2]); h[3] = f2bf(v[3]);
      bh[mf][na] = h;
      if constexpr (WITH_S) {
        if (na == 0) s[mf] = v;
        else { s[mf][0] += v[0]; s[mf][1] += v[1]; s[mf][2] += v[2]; s[mf][3] += v[3]; }
      }
    }
  }
  if constexpr (WITH_S) {
    // sum over the 16 agent columns (xor bits 0..3 never cross quads)
#pragma unroll
    for (int st = 1; st < 16; st <<= 1)
#pragma unroll
      for (int mf = 0; mf < 4; mf++)
#pragma unroll
        for (int r2 = 0; r2 < 4; r2++) s[mf][r2] += __shfl_xor(s[mf][r2], st);
#pragma unroll
    for (int mf = 0; mf < 4; mf++) {
      bf16x4 t; t[0] = f2bf(s[mf][0]); t[1] = f2bf(s[mf][1]);
      t[2] = f2bf(s[mf][2]); t[3] = f2bf(s[mf][3]);
      bs[mf] = t;   // identical in all 16 cols == replicated S chunk, as the MFMA needs
    }
  }
}

__global__ void __launch_bounds__(256, 2) commnet_main(
    const float* __restrict__ obs,
    const float* __restrict__ enc_b,
    const float* __restrict__ comm_b,
    const float* __restrict__ ob1,
    const float* __restrict__ ob2,
    const int* __restrict__ avail,
    const short* __restrict__ wfr,
    float* __restrict__ out) {
  __shared__ short lw[50 * 512];   // 51200 B weight pair-frags
  __shared__ float lb[272];        // 0:enc_b 64:comm_b(128) 192:out_b1 256:out_b2
  const int tid = threadIdx.x, wave = tid >> 6, lane = tid & 63;
  const int quad = lane >> 4, col = lane & 15;
  const bf16x8* wf8 = (const bf16x8*)wfr;

#pragma unroll 1
  for (int f = wave; f < 50; f += 4)
    *(bf16x8*)(lw + f * 512 + lane * 8) = wf8[f * 64 + lane];
  if (tid < 64)        lb[tid] = enc_b[tid];
  else if (tid < 192)  lb[tid] = comm_b[tid - 64];
  else if (tid < 256)  lb[tid] = ob1[tid - 192];
  if (tid < 16)        lb[256 + tid] = ob2[tid];

  const int b = blockIdx.x * 4 + wave;   // grid 4096 x 4 waves: one batch per wave

  // input loads issued before the barrier (independent of LDS staging);
  // obs converted to bf16 immediately after -> the f32 temps die at the top.
  i32x4 pav[2];
  f32x4 po[2][4];
#pragma unroll
  for (int na = 0; na < 2; na++) {
#pragma unroll
    for (int k = 0; k < 4; k++)
      po[na][k] = *(const f32x4*)(obs + ((b * 32 + na * 16 + col) * 64 + k * 16 + quad * 4));
    pav[na] = *(const i32x4*)(avail + ((b * 32 + na * 16 + col) * 16 + quad * 4));
  }

  bf16x4 bh[4][2], bs[4];
#pragma unroll
  for (int k = 0; k < 4; k++)
#pragma unroll
    for (int na = 0; na < 2; na++) {
      f32x4 x = po[na][k];
      bf16x4 h; h[0] = f2bf(x[0]); h[1] = f2bf(x[1]); h[2] = f2bf(x[2]); h[3] = f2bf(x[3]);
      bh[k][na] = h;
    }

  __syncthreads();   // lds_w/lb fully staged

  const f32x4 z4 = {0.f, 0.f, 0.f, 0.f};
  f32x4 ya[4][2];

  // ---------------- GEMM1: h0^T = relu(enc_w^T obs^T + b) ----------------
#pragma unroll
  for (int mf = 0; mf < 4; mf++) { ya[mf][0] = z4; ya[mf][1] = z4; }
#pragma unroll
  for (int kp = 0; kp < 2; kp++)
#pragma unroll
    for (int mf = 0; mf < 4; mf++) {
      bf16x8 P = *(const bf16x8*)(lw + (kp * 4 + mf) * 512 + lane * 8);
      bf16x4 A0 = plo(P), A1 = phi(P);
#pragma unroll
      for (int na = 0; na < 2; na++) {
        ya[mf][na] = MFMA16(A0, bh[2 * kp][na], ya[mf][na]);
        ya[mf][na] = MFMA16(A1, bh[2 * kp + 1][na], ya[mf][na]);
      }
    }
  stage16<true>(ya, lb + 0, quad, bh, bs);

  // -------- comm rounds: Y^T = W_eff^T H^T + V^T S 1^T + b (S via extra K) ----
#pragma unroll
  for (int r = 0; r < 2; r++) {
#pragma unroll
    for (int mf = 0; mf < 4; mf++) { ya[mf][0] = z4; ya[mf][1] = z4; }
#pragma unroll
    for (int kp = 0; kp < 2; kp++)
#pragma unroll
      for (int mf = 0; mf < 4; mf++) {
        bf16x8 P = *(const bf16x8*)(lw + (8 + r * 8 + kp * 4 + mf) * 512 + lane * 8);
        bf16x8 Q = *(const bf16x8*)(lw + (24 + r * 8 + kp * 4 + mf) * 512 + lane * 8);
        bf16x4 W0 = plo(P), W1 = phi(P), V0 = plo(Q), V1 = phi(Q);
#pragma unroll
        for (int na = 0; na < 2; na++) {
          ya[mf][na] = MFMA16(W0, bh[2 * kp][na], ya[mf][na]);
          ya[mf][na] = MFMA16(W1, bh[2 * kp + 1][na], ya[mf][na]);
          ya[mf][na] = MFMA16(V0, bs[2 * kp], ya[mf][na]);
          ya[mf][na] = MFMA16(V1, bs[2 * kp + 1], ya[mf][na]);
        }
      }
    if (r == 0) stage16<true>(ya, lb + 64, quad, bh, bs);
    else        stage16<false>(ya, lb + 128, quad, bh, bs);
  }

  // ---------------- out1: hid^T = relu(w1^T h^T + b1) ---------------------
#pragma unroll
  for (int mf = 0; mf < 4; mf++) { ya[mf][0] = z4; ya[mf][1] = z4; }
#pragma unroll
  for (int kp = 0; kp < 2; kp++)
#pragma unroll
    for (int mf = 0; mf < 4; mf++) {
      bf16x8 P = *(const bf16x8*)(lw + (40 + kp * 4 + mf) * 512 + lane * 8);
      bf16x4 A0 = plo(P), A1 = phi(P);
#pragma unroll
      for (int na = 0; na < 2; na++) {
        ya[mf][na] = MFMA16(A0, bh[2 * kp][na], ya[mf][na]);
        ya[mf][na] = MFMA16(A1, bh[2 * kp + 1][na], ya[mf][na]);
      }
    }
  stage16<false>(ya, lb + 192, quad, bh, bs);

  // ---------------- out2 + mask + vectorized store ------------------------
  f32x4 q[2] = {z4, z4};
#pragma unroll
  for (int kp = 0; kp < 2; kp++) {
    bf16x8 P = *(const bf16x8*)(lw + (48 + kp) * 512 + lane * 8);
    bf16x4 A0 = plo(P), A1 = phi(P);
#pragma unroll
    for (int na = 0; na < 2; na++) {
      q[na] = MFMA16(A0, bh[2 * kp][na], q[na]);
      q[na] = MFMA16(A1, bh[2 * kp + 1][na], q[na]);
    }
  }
  f32x4 obv = *(const f32x4*)(lb + 256 + quad * 4);
#pragma unroll
  for (int na = 0; na < 2; na++) {
    int base = (b * 32 + na * 16 + col) * 16 + quad * 4;
    f32x4 v;
#pragma unroll
    for (int r2 = 0; r2 < 4; r2++)
      v[r2] = (pav[na][r2] == 0) ? -1e10f : (q[na][r2] + obv[r2]);
    *(f32x4*)(out + base) = v;
  }
}

extern "C" void kernel_launch(void* const* d_in, const int* in_sizes, int n_in,
                              void* d_out, int out_size, void* d_ws, size_t ws_size,
                              hipStream_t stream) {
  const float* obs    = (const float*)d_in[0];
  const float* enc_w  = (const float*)d_in[1];
  const float* enc_b  = (const float*)d_in[2];
  const float* comm_w = (const float*)d_in[3];
  const float* comm_b = (const float*)d_in[4];
  const float* out_w1 = (const float*)d_in[5];
  const float* out_b1 = (const float*)d_in[6];
  const float* out_w2 = (const float*)d_in[7];
  const float* out_b2 = (const float*)d_in[8];
  const int*   avail  = (const int*)d_in[9];
  short* wf = (short*)d_ws;  // 50 pair-frags * 512 bf16 = 51200 B scratch

  build_frags<<<100, 256, 0, stream>>>(enc_w, comm_w, out_w1, out_w2, wf);
  commnet_main<<<4096, 256, 0, stream>>>(obs, enc_b, comm_b, out_b1, out_b2, avail, wf,
                                         (float*)d_out);
}